// Round 3
// baseline (261.364 us; speedup 1.0000x reference)
//
#include <hip/hip_runtime.h>
#include <stdint.h>

// NMU forward: y[b,o] = prod_d( clip(M[d,o],0,1)*x[b,d] + 1-clip(M[d,o],0,1) )
// B=16384, D=256, O=32, fp32.
//
// R3: same DMA-staged structure as R2 (global_load_lds double-buffer for x),
// but with the register working set cut to fit: M is cached 8 d's at a time
// (mh[8]+om[8] = 16 VGPRs) instead of 32 (64 VGPRs -> 256-VGPR + 157 MB of
// scratch spills in R2). Rows stay inner (R=4) to amortize the M clamp work.

constexpr int D = 256;
constexpr int O = 32;
constexpr int SLOTS = 8;                 // 256 threads / 32 o-lanes
constexpr int R = 4;                     // rows per thread
constexpr int ROWS = SLOTS * R;          // 32 rows per block
constexpr int DC = 64;                   // d's per staged x chunk
constexpr int NCHUNK = D / DC;           // 4
constexpr int F4_PER_ROW = DC / 4;       // 16
constexpr int CHUNK_F4 = ROWS * F4_PER_ROW;   // 512 float4 per buffer
constexpr int DM = 8;                    // d's of M register-cached at a time

__device__ __forceinline__ void async16(const float* g, float* l) {
    __builtin_amdgcn_global_load_lds(
        (const __attribute__((address_space(1))) uint32_t*)g,
        (__attribute__((address_space(3))) uint32_t*)l, 16, 0, 0);
}

__global__ __launch_bounds__(256, 2) void nmu_fwd(const float* __restrict__ x,
                                                  const float* __restrict__ M,
                                                  float* __restrict__ y)
{
    __shared__ float xb[2][ROWS * DC];   // 2 x 8 KB
    const int tid  = threadIdx.x;
    const int o    = tid & 31;
    const int slot = tid >> 5;
    const int row0 = blockIdx.x * ROWS;

    // Two staging slots per thread; addresses precomputed once.
    const int f0 = tid;              // flat float4 index, issue 0
    const int f1 = 256 + tid;        // issue 1
    const float* g0 = x + (row0 + (f0 >> 4)) * D + (f0 & 15) * 4;
    const float* g1 = x + (row0 + (f1 >> 4)) * D + (f1 & 15) * 4;

    float prod[R];
#pragma unroll
    for (int i = 0; i < R; ++i) prod[i] = 1.0f;

    // Stage chunk 0 into buffer 0.
    async16(g0, &xb[0][f0 * 4]);
    async16(g1, &xb[0][f1 * 4]);
    __syncthreads();                 // vmcnt drained before barrier

#pragma unroll
    for (int k = 0; k < NCHUNK; ++k) {
        if (k + 1 < NCHUNK) {        // prefetch next chunk into other buffer
            const int kk = (k + 1) & 1;
            async16(g0 + (k + 1) * DC, &xb[kk][f0 * 4]);
            async16(g1 + (k + 1) * DC, &xb[kk][f1 * 4]);
        }
        const float* buf = xb[k & 1];

#pragma unroll
        for (int s = 0; s < DC / DM; ++s) {      // 8 sub-chunks of 8 d's
            float mh[DM], om[DM];
            const int d0 = k * DC + s * DM;
#pragma unroll
            for (int j = 0; j < DM; ++j) {
                float v = M[(d0 + j) * O + o];    // 128B wave-broadcast, L1/L2
                v = __builtin_amdgcn_fmed3f(v, 0.0f, 1.0f);
                mh[j] = v;
                om[j] = 1.0f - v;
            }
#pragma unroll
            for (int i = 0; i < R; ++i) {
                const int r = slot + i * SLOTS;
                const float4* xp =
                    reinterpret_cast<const float4*>(buf + r * DC + s * DM);
                float4 xa = xp[0];                // ds_read_b128, 2-way alias
                float4 xc = xp[1];
                float t0 = fmaf(xa.x, mh[0], om[0]);
                float t1 = fmaf(xa.y, mh[1], om[1]);
                float t2 = fmaf(xa.z, mh[2], om[2]);
                float t3 = fmaf(xa.w, mh[3], om[3]);
                float u0 = fmaf(xc.x, mh[4], om[4]);
                float u1 = fmaf(xc.y, mh[5], om[5]);
                float u2 = fmaf(xc.z, mh[6], om[6]);
                float u3 = fmaf(xc.w, mh[7], om[7]);
                prod[i] *= ((t0 * t1) * (t2 * t3)) * ((u0 * u1) * (u2 * u3));
            }
        }
        __syncthreads();             // next buffer ready / this one reusable
    }

#pragma unroll
    for (int i = 0; i < R; ++i)
        y[(row0 + slot + i * SLOTS) * O + o] = prod[i];   // coalesced per row
}

extern "C" void kernel_launch(void* const* d_in, const int* in_sizes, int n_in,
                              void* d_out, int out_size, void* d_ws, size_t ws_size,
                              hipStream_t stream) {
    const float* x = (const float*)d_in[0];   // [B, 256]
    const float* M = (const float*)d_in[1];   // [256, 32]
    float* y = (float*)d_out;                 // [B, 32]
    const int B = in_sizes[0] / D;            // 16384
    dim3 grid(B / ROWS);                      // 512 blocks = 2 blocks/CU
    nmu_fwd<<<grid, 256, 0, stream>>>(x, M, y);
}

// Round 4
// 84.124 us; speedup vs baseline: 3.1069x; 3.1069x over previous
//
#include <hip/hip_runtime.h>

// NMU forward: y[b,o] = prod_d( clip(M[d,o],0,1)*x[b,d] + 1-clip(M[d,o],0,1) )
// B=16384, D=256, O=32, fp32.
//
// R4: back to R1's direct-load structure (global_load_lds staging was a
// 6x regression in R2/R3). Fixes R1's latency problem with parallelism:
//  - D split across half-waves: lanes 0-31 do d in [0,128), lanes 32-63 do
//    [128,256); partial products merged with one __shfl_xor(.,32) + mul.
//  - R=2 rows/wave -> 8 rows/block -> 2048 blocks = 8 blocks/CU (4x R1).
//  - float2 inner math so LLVM can use packed fp32 (v_pk_fma_f32 et al).
//  - #pragma unroll 2 on the chunk loop: enough loads in flight for latency,
//    bounded register pressure (full unroll caused R2's 256-VGPR spills).

typedef float v2f __attribute__((ext_vector_type(2)));

constexpr int D    = 256;
constexpr int O    = 32;
constexpr int R    = 2;          // rows per wave
constexpr int ROWS = 4 * R;      // 8 rows per 256-thread block
constexpr int HD   = D / 2;      // 128 d's per half-wave
constexpr int DM   = 8;          // d's per chunk

__global__ __launch_bounds__(256, 4) void nmu_fwd(const float* __restrict__ x,
                                                  const float* __restrict__ M,
                                                  float* __restrict__ y)
{
    const int tid  = threadIdx.x;
    const int o    = tid & 31;          // output column
    const int h    = (tid >> 5) & 1;    // D-half
    const int w    = tid >> 6;          // wave within block
    const int row0 = blockIdx.x * ROWS + w * R;

    const float* xr0 = x + row0 * D + h * HD;   // my half of row0's x
    const float* xr1 = xr0 + D;                 // row0+1
    const float* Mp  = M + (h * HD) * O + o;    // my column, my half

    v2f p0 = {1.0f, 1.0f};   // even/odd-d partial product chains, row 0
    v2f p1 = {1.0f, 1.0f};   // row 1

#pragma unroll 2
    for (int c = 0; c < HD / DM; ++c) {         // 16 chunks of 8 d's
        // M prep: clamp + complement, as float2 (even,odd) pairs
        v2f mh[DM / 2], om[DM / 2];
#pragma unroll
        for (int j = 0; j < DM / 2; ++j) {
            float a = Mp[(c * DM + 2 * j    ) * O];
            float b = Mp[(c * DM + 2 * j + 1) * O];
            v2f v = {a, b};
            v = __builtin_elementwise_max(v, (v2f)0.0f);
            v = __builtin_elementwise_min(v, (v2f)1.0f);
            mh[j] = v;
            om[j] = (v2f)1.0f - v;
        }

        const float4* xp0 = reinterpret_cast<const float4*>(xr0 + c * DM);
        const float4* xp1 = reinterpret_cast<const float4*>(xr1 + c * DM);
        float4 A0 = xp0[0], B0 = xp0[1];        // row0: d..d+7 (broadcast/o-group)
        float4 A1 = xp1[0], B1 = xp1[1];        // row1

        {   // row 0: 4 pk_fma + 4 pk_mul for 8 d's
            v2f t0 = {A0.x, A0.y}, t1 = {A0.z, A0.w};
            v2f t2 = {B0.x, B0.y}, t3 = {B0.z, B0.w};
            t0 = __builtin_elementwise_fma(t0, mh[0], om[0]);
            t1 = __builtin_elementwise_fma(t1, mh[1], om[1]);
            t2 = __builtin_elementwise_fma(t2, mh[2], om[2]);
            t3 = __builtin_elementwise_fma(t3, mh[3], om[3]);
            p0 *= (t0 * t1) * (t2 * t3);
        }
        {   // row 1
            v2f t0 = {A1.x, A1.y}, t1 = {A1.z, A1.w};
            v2f t2 = {B1.x, B1.y}, t3 = {B1.z, B1.w};
            t0 = __builtin_elementwise_fma(t0, mh[0], om[0]);
            t1 = __builtin_elementwise_fma(t1, mh[1], om[1]);
            t2 = __builtin_elementwise_fma(t2, mh[2], om[2]);
            t3 = __builtin_elementwise_fma(t3, mh[3], om[3]);
            p1 *= (t0 * t1) * (t2 * t3);
        }
    }

    // fold even/odd chains, then merge the two D-halves across the wave
    float q0 = p0.x * p0.y;
    float q1 = p1.x * p1.y;
    q0 *= __shfl_xor(q0, 32, 64);
    q1 *= __shfl_xor(q1, 32, 64);

    if (h == 0) {                        // lanes 0-31: coalesced 128B stores
        y[(row0    ) * O + o] = q0;
        y[(row0 + 1) * O + o] = q1;
    }
}

extern "C" void kernel_launch(void* const* d_in, const int* in_sizes, int n_in,
                              void* d_out, int out_size, void* d_ws, size_t ws_size,
                              hipStream_t stream) {
    const float* x = (const float*)d_in[0];   // [B, 256]
    const float* M = (const float*)d_in[1];   // [256, 32]
    float* y = (float*)d_out;                 // [B, 32]
    const int B = in_sizes[0] / D;            // 16384
    dim3 grid(B / ROWS);                      // 2048 blocks = 8 blocks/CU
    nmu_fwd<<<grid, 256, 0, stream>>>(x, M, y);
}

// Round 5
// 83.277 us; speedup vs baseline: 3.1385x; 1.0102x over previous
//
#include <hip/hip_runtime.h>
#include <stdint.h>

// NMU forward: y[b,o] = prod_d( clip(M[d,o],0,1)*x[b,d] + 1-clip(M[d,o],0,1) )
// B=16384, D=256, O=32, fp32.
//
// R5: inverted layout. lane = row (64 rows/wave), o in registers (32 fp32
// accumulators). x loads are per-lane float4 (1 KB/instr, 8 per thread).
// M is wave-uniform -> scalar path: prologue clamps M into ws (MH), main
// kernel reads MH via an addrspace(4) constant pointer with a
// readfirstlane-uniform base so the backend emits s_load (SGPR broadcasts,
// zero VMEM). Identity m*x+(1-m) = m*(x-1)+1 removes the om array: per d per
// o-pair exactly one v_pk_fma_f32 (scalar operand = m pair, c = inline 1.0)
// and one v_pk_mul_f32. D split across the 8 waves of a 512-thread block;
// partial products combined via LDS (row stride 260 floats: 16B-aligned,
// b128 ops at their 8-cycle floor).

typedef float v2f __attribute__((ext_vector_type(2)));
typedef __attribute__((address_space(4))) const float kfloat;  // constant AS

constexpr int D = 256;
constexpr int O = 32;
constexpr int ROWS = 64;                 // rows per block (= lanes per wave)
constexpr int SEGS = 8;                  // waves per block = D segments
constexpr int SEG_D = D / SEGS;          // 32 d's per wave
constexpr int LSTR = SEGS * O + 4;       // 260 floats: aligned + conflict-free
constexpr int NBLK = 16384 / ROWS;       // 256 blocks = 1 per CU

__global__ __launch_bounds__(256) void nmu_prep(const float* __restrict__ M,
                                                float* __restrict__ MH) {
    const int i = blockIdx.x * 256 + threadIdx.x;     // 8192 elements
    MH[i] = __builtin_amdgcn_fmed3f(M[i], 0.0f, 1.0f);
}

__global__ __launch_bounds__(512) void nmu_main(const float* __restrict__ x,
                                                const float* __restrict__ MH,
                                                float* __restrict__ y) {
    __shared__ float part[ROWS * LSTR];               // 66560 B
    const int tid  = threadIdx.x;
    const int lane = tid & 63;                        // my row within block
    const int w    = tid >> 6;                        // wave id = d-segment
    const int row0 = blockIdx.x * ROWS;

    // Wave-uniform constant-AS view of this wave's MH segment (32 d x 32 o).
    const int segbase = __builtin_amdgcn_readfirstlane(w * SEG_D * O);
    kfloat* mc = (kfloat*)(uintptr_t)MH + segbase;

    const float4* xp = reinterpret_cast<const float4*>(
        x + (row0 + lane) * D + w * SEG_D);           // my row, my 128B slice

    v2f prod[O / 2];
#pragma unroll
    for (int i = 0; i < O / 2; ++i) prod[i] = (v2f){1.0f, 1.0f};

#pragma unroll 2
    for (int q = 0; q < SEG_D / 4; ++q) {             // 8 iters, 4 d's each
        const float4 xv = xp[q];
        const float xs[4] = {xv.x, xv.y, xv.z, xv.w};
#pragma unroll
        for (int j = 0; j < 4; ++j) {
            const float xm1 = xs[j] - 1.0f;           // m*(x-1)+1 == m*x+1-m
            const v2f xm1v = {xm1, xm1};
            const int dbase = (q * 4 + j) * O;
#pragma unroll
            for (int op = 0; op < O / 2; ++op) {
                v2f mh;                                // SGPR pair via s_load
                mh.x = mc[dbase + 2 * op];
                mh.y = mc[dbase + 2 * op + 1];
                v2f t = mh * xm1v + (v2f){1.0f, 1.0f}; // v_pk_fma_f32
                prod[op] *= t;                         // v_pk_mul_f32
            }
        }
    }

    // Stash partial products: part[row][seg*32 + o], row stride 260 floats.
    float* pb = &part[lane * LSTR + w * O];
#pragma unroll
    for (int o4 = 0; o4 < 8; ++o4) {
        float4 v = {prod[2 * o4].x, prod[2 * o4].y,
                    prod[2 * o4 + 1].x, prod[2 * o4 + 1].y};
        *reinterpret_cast<float4*>(pb + o4 * 4) = v;   // ds_write_b128
    }
    __syncthreads();

    // Combine 8 segments: 512 threads x 4 outputs = 64 rows x 32 o.
    const int row = tid >> 3;
    const int o4  = tid & 7;
    const float* cb = &part[row * LSTR + o4 * 4];
    float4 acc = *reinterpret_cast<const float4*>(cb);
#pragma unroll
    for (int s = 1; s < SEGS; ++s) {
        float4 v = *reinterpret_cast<const float4*>(cb + s * O);
        acc.x *= v.x; acc.y *= v.y; acc.z *= v.z; acc.w *= v.w;
    }
    *reinterpret_cast<float4*>(y + (row0 + row) * O + o4 * 4) = acc;  // 16B/lane
}

extern "C" void kernel_launch(void* const* d_in, const int* in_sizes, int n_in,
                              void* d_out, int out_size, void* d_ws, size_t ws_size,
                              hipStream_t stream) {
    const float* x = (const float*)d_in[0];   // [16384, 256]
    const float* M = (const float*)d_in[1];   // [256, 32]
    float* y  = (float*)d_out;                // [16384, 32]
    float* MH = (float*)d_ws;                 // 32 KB clamped-M scratch

    nmu_prep<<<dim3(D * O / 256), 256, 0, stream>>>(M, MH);
    nmu_main<<<dim3(NBLK), 512, 0, stream>>>(x, MH, y);
}

// Round 6
// 80.390 us; speedup vs baseline: 3.2512x; 1.0359x over previous
//
#include <hip/hip_runtime.h>

// NMU forward: y[b,o] = prod_d( clip(M[d,o],0,1)*x[b,d] + 1-clip(M[d,o],0,1) )
// B=16384, D=256, O=32, fp32.
//
// R6: M RESIDENT IN REGISTERS. R1/R4/R5 all plateaued at ~33 us because M
// was re-fetched in the inner loop (per-lane VMEM or s_load round trips).
// Here lane = (o, d-half): each thread holds its M column-half as 64 packed
// v2f pairs (128 VGPRs), clamped once in the prologue. Identity
// m*x+(1-m) = m*(x-1)+1 eliminates the om array. Inner loop is pure VALU
// (pk_fma/pk_mul) against resident M; x streams in as float4 broadcasts
// (32 o-lanes share each address -> 1 transaction), chunk-prefetched.
// d-halves merged with one __shfl_xor(32). No LDS, no workspace.

typedef float v2f __attribute__((ext_vector_type(2)));

constexpr int D  = 256;
constexpr int O  = 32;
constexpr int HD = D / 2;              // 128 d's per half-wave
constexpr int ROWS_PW = 8;             // rows per wave
constexpr int WAVES   = 4;             // per block (256 threads)
constexpr int ROWS_PB = ROWS_PW * WAVES;   // 32 rows per block

__global__ __launch_bounds__(256, 2)
void nmu_fwd(const float* __restrict__ x, const float* __restrict__ M,
             float* __restrict__ y)
{
    const int tid  = threadIdx.x;
    const int lane = tid & 63;
    const int w    = tid >> 6;
    const int o    = lane & 31;        // output column (coalescing dim)
    const int dh   = lane >> 5;        // d-half: 0 -> d in [0,128), 1 -> [128,256)
    const int row0 = blockIdx.x * ROWS_PB + w * ROWS_PW;

    // ---- Prologue: clamp my M column-half into 64 resident v2f pairs ----
    v2f m[HD / 2];                     // 128 VGPRs, live for the whole kernel
    const float* Mp = M + (dh * HD) * O + o;
#pragma unroll
    for (int j = 0; j < HD / 2; ++j) { // 128 coalesced dword loads (once)
        float a = Mp[(2 * j    ) * O];
        float b = Mp[(2 * j + 1) * O];
        m[j].x = __builtin_amdgcn_fmed3f(a, 0.0f, 1.0f);
        m[j].y = __builtin_amdgcn_fmed3f(b, 0.0f, 1.0f);
    }

    const float* xbase = x + dh * HD;

#pragma unroll 1                       // rows sequential: bounds VGPR pressure
    for (int r = 0; r < ROWS_PW; ++r) {
        const int row = row0 + r;
        const float4* xp = reinterpret_cast<const float4*>(xbase + row * D);

        // chunk = 8 float4 = 32 d's (one 128B line per d-half); explicit
        // next-chunk prefetch overlaps VMEM latency with compute.
        float4 cur[8], nxt[8];
#pragma unroll
        for (int u = 0; u < 8; ++u) cur[u] = xp[u];

        v2f p = {1.0f, 1.0f};
#pragma unroll
        for (int c = 0; c < 4; ++c) {  // 4 chunks of 32 d's
            if (c < 3) {
#pragma unroll
                for (int u = 0; u < 8; ++u) nxt[u] = xp[(c + 1) * 8 + u];
            }
            v2f t[16];
#pragma unroll
            for (int u = 0; u < 8; ++u) {
                const int f = c * 8 + u;               // float4 index in row-half
                v2f x01 = {cur[u].x - 1.0f, cur[u].y - 1.0f};
                v2f x23 = {cur[u].z - 1.0f, cur[u].w - 1.0f};
                t[2 * u]     = m[2 * f]     * x01 + (v2f){1.0f, 1.0f}; // pk_fma
                t[2 * u + 1] = m[2 * f + 1] * x23 + (v2f){1.0f, 1.0f};
            }
            // tree-fold 16 -> 1 (keeps the dep chain on p at 1 mul per chunk)
#pragma unroll
            for (int i = 0; i < 8; ++i) t[i] *= t[i + 8];
#pragma unroll
            for (int i = 0; i < 4; ++i) t[i] *= t[i + 4];
            t[0] *= t[2]; t[1] *= t[3];
            p *= t[0] * t[1];
#pragma unroll
            for (int u = 0; u < 8; ++u) cur[u] = nxt[u];
        }

        float s = p.x * p.y;           // fold even/odd d chains
        s *= __shfl_xor(s, 32, 64);    // merge the two d-halves
        if (dh == 0)
            y[row * O + o] = s;        // 32 lanes x 4B contiguous = 128B store
    }
}

extern "C" void kernel_launch(void* const* d_in, const int* in_sizes, int n_in,
                              void* d_out, int out_size, void* d_ws, size_t ws_size,
                              hipStream_t stream) {
    const float* x = (const float*)d_in[0];   // [16384, 256]
    const float* M = (const float*)d_in[1];   // [256, 32]
    float* y = (float*)d_out;                 // [16384, 32]
    const int B = in_sizes[0] / D;            // 16384
    dim3 grid(B / ROWS_PB);                   // 512 blocks = 2 blocks/CU
    nmu_fwd<<<grid, 256, 0, stream>>>(x, M, y);
}

// Round 7
// 73.059 us; speedup vs baseline: 3.5775x; 1.1003x over previous
//
#include <hip/hip_runtime.h>

// NMU forward: y[b,o] = prod_d( clip(M[d,o],0,1)*x[b,d] + 1-clip(M[d,o],0,1) )
// B=16384, D=256, O=32, fp32.
//
// R7: R6's resident-M compute layout + LDS-staged x.
// Diagnosis history: R1/R4 (per-lane M refetch), R5 (s_load M round trips),
// R6 (broadcast-x: only 2 HBM lines in flight per wave) all ~30 us. Fix:
//  - x staged global->LDS with per-lane coalesced float4 loads via VGPR
//    transit (8 instrs x 1 KB, all independent -> 32 KB/block in flight;
//    NOT global_load_lds, which regressed 6x in R2/R3).
//  - compute reads x from LDS as broadcasts (32 o-lanes share the address;
//    the 2 d-half addresses alias the same banks -> 2-way, free per m136).
//  - M column-half resident in 128 VGPRs, clamped once; t = m*(x-1)+1
//    kills the om array (one pk_fma + one pk_mul per packed d-pair).

typedef float v2f __attribute__((ext_vector_type(2)));

constexpr int D  = 256;
constexpr int O  = 32;
constexpr int HD = D / 2;               // 128 d's per d-half lane group
constexpr int ROWS_PW = 8;              // rows per wave
constexpr int WAVES   = 4;              // 256 threads
constexpr int ROWS_PB = ROWS_PW * WAVES;  // 32 rows per block
constexpr int TILE_F4 = ROWS_PB * D / 4;  // 2048 float4 = 32 KB

__global__ __launch_bounds__(256, 2)
void nmu_fwd(const float* __restrict__ x, const float* __restrict__ M,
             float* __restrict__ y)
{
    __shared__ __align__(16) float xs[ROWS_PB * D];   // 32 KB x tile
    const int tid  = threadIdx.x;
    const int lane = tid & 63;
    const int w    = tid >> 6;
    const int o    = lane & 31;          // output column
    const int dh   = lane >> 5;          // d-half
    const int row0 = blockIdx.x * ROWS_PB;

    // ---- M prologue: my column-half -> 64 resident v2f (128 VGPRs) ----
    // Issued first (oldest outstanding); L2-hot after the first blocks.
    const float* Mp = M + (dh * HD) * O + o;
    v2f m[HD / 2];
#pragma unroll
    for (int j = 0; j < HD / 2; ++j) {
        float a = Mp[(2 * j    ) * O];
        float b = Mp[(2 * j + 1) * O];
        m[j].x = __builtin_amdgcn_fmed3f(a, 0.0f, 1.0f);
        m[j].y = __builtin_amdgcn_fmed3f(b, 0.0f, 1.0f);
    }

    // ---- Stage x tile: 8 independent 1KB-coalesced loads per thread ----
    const float4* xg = reinterpret_cast<const float4*>(x + row0 * D);
    float4* lp = reinterpret_cast<float4*>(xs);
    float4 st[8];
#pragma unroll
    for (int i = 0; i < 8; ++i) st[i] = xg[i * 256 + tid];
#pragma unroll
    for (int i = 0; i < 8; ++i) lp[i * 256 + tid] = st[i];   // conflict-free
    __syncthreads();

    // ---- Compute: 8 rows per wave, x from LDS broadcasts ----
#pragma unroll 1
    for (int r = 0; r < ROWS_PW; ++r) {
        const int row = w * ROWS_PW + r;                 // row within tile
        const float4* xr = reinterpret_cast<const float4*>(
            xs + row * D + dh * HD);                     // my half: 32 f4

        v2f p = {1.0f, 1.0f};
#pragma unroll
        for (int c = 0; c < 4; ++c) {                    // 4 chunks of 8 f4
            float4 xv[8];
#pragma unroll
            for (int u = 0; u < 8; ++u) xv[u] = xr[c * 8 + u];  // ds_read_b128
            v2f t[16];
#pragma unroll
            for (int u = 0; u < 8; ++u) {
                const int f = c * 8 + u;
                v2f x01 = {xv[u].x - 1.0f, xv[u].y - 1.0f};
                v2f x23 = {xv[u].z - 1.0f, xv[u].w - 1.0f};
                t[2 * u]     = m[2 * f]     * x01 + (v2f){1.0f, 1.0f};
                t[2 * u + 1] = m[2 * f + 1] * x23 + (v2f){1.0f, 1.0f};
            }
#pragma unroll
            for (int i = 0; i < 8; ++i) t[i] *= t[i + 8];
#pragma unroll
            for (int i = 0; i < 4; ++i) t[i] *= t[i + 4];
            t[0] *= t[2]; t[1] *= t[3];
            p *= t[0] * t[1];                            // 1 dep-mul per chunk
        }

        float s = p.x * p.y;                             // fold even/odd d
        s *= __shfl_xor(s, 32, 64);                      // merge d-halves
        if (dh == 0)
            y[(row0 + row) * O + o] = s;                 // 128B per row store
    }
}

extern "C" void kernel_launch(void* const* d_in, const int* in_sizes, int n_in,
                              void* d_out, int out_size, void* d_ws, size_t ws_size,
                              hipStream_t stream) {
    const float* x = (const float*)d_in[0];   // [16384, 256]
    const float* M = (const float*)d_in[1];   // [256, 32]
    float* y = (float*)d_out;                 // [16384, 32]
    const int B = in_sizes[0] / D;            // 16384
    dim3 grid(B / ROWS_PB);                   // 512 blocks = 2 blocks/CU
    nmu_fwd<<<grid, 256, 0, stream>>>(x, M, y);
}